// Round 1
// baseline (1384.722 us; speedup 1.0000x reference)
//
#include <hip/hip_runtime.h>

#define CIN 32
#define COUT 64
#define OD0 100
#define OD1 100
#define OD2 8
#define IZ 200
#define IY 200
#define IX 16
#define NTAP 27

// ---------- rank selection: two-level 16-bit radix histograms ----------

__global__ void hist_hi_kernel(const float* __restrict__ mask, int n, int* __restrict__ hist) {
    int i = blockIdx.x * blockDim.x + threadIdx.x;
    if (i >= n) return;
    unsigned bits = __float_as_uint(mask[i]);   // mask in [0,1): uint order == float order
    atomicAdd(&hist[bits >> 16], 1);
}

__global__ void hist_lo_kernel(const float* __restrict__ mask, int n,
                               const int* __restrict__ sel, int* __restrict__ hist) {
    int i = blockIdx.x * blockDim.x + threadIdx.x;
    if (i >= n) return;
    unsigned bits = __float_as_uint(mask[i]);
    if ((int)(bits >> 16) == sel[0]) atomicAdd(&hist[bits & 0xFFFFu], 1);
}

// One block, 256 threads. Finds bucket containing `rank` and residual rank.
__global__ void select_kernel(const int* __restrict__ hist, const int* rankSrc,
                              int rankConst, int* outPair) {
    __shared__ int partial[256];
    __shared__ int scan[257];
    int t = threadIdx.x;
    int rank = rankSrc ? *rankSrc : rankConst;
    const int* h = hist + t * 256;
    int sum = 0;
    for (int j = 0; j < 256; j++) sum += h[j];
    partial[t] = sum;
    __syncthreads();
    if (t == 0) {
        int c = 0;
        for (int j = 0; j < 256; j++) { scan[j] = c; c += partial[j]; }
        scan[256] = c;
    }
    __syncthreads();
    int base = scan[t];
    if (rank >= base && rank < scan[t + 1]) {
        int c = base;
        for (int j = 0; j < 256; j++) {
            int hv = h[j];
            if (rank < c + hv) { outPair[0] = t * 256 + j; outPair[1] = rank - c; break; }
            c += hv;
        }
    }
}

// ---------- gather-path helper kernels ----------

// W (27,32,64) -> Wt (27,64,32): lane-contiguous weight fragments.
__global__ void transpose_w_kernel(const float* __restrict__ W, float* __restrict__ Wt) {
    int i = blockIdx.x * blockDim.x + threadIdx.x;
    if (i >= NTAP * CIN * COUT) return;
    int cout = i % COUT;
    int rest = i / COUT;
    int cin = rest % CIN;
    int tap = rest / CIN;
    Wt[((size_t)tap * COUT + cout) * CIN + cin] = W[i];
}

// Dense input grid: head[cell] -> last point index, next[] chains collisions.
__global__ void build_grid_kernel(const int* __restrict__ coors, int n,
                                  int* __restrict__ head, int* __restrict__ next) {
    int i = blockIdx.x * blockDim.x + threadIdx.x;
    if (i >= n) return;
    const int4 c = ((const int4*)coors)[i];
    int cell = ((c.x * IZ + c.y) * IY + c.z) * IX + c.w;
    next[i] = atomicExch(&head[cell], i);
}

// ---------- main gather conv: one wave per output cell, lane = cout ----------
// Output cell oc gathers input pos = 2*oc - 1 + off, off in [0,3)  (stride-2, pad-1).
// No atomics: register accumulate, single plain store. Prune fused into store.

__global__ void __launch_bounds__(256)
gather_kernel(const float* __restrict__ feat, const float* __restrict__ mask,
              const float* __restrict__ Wt, const int* __restrict__ sel,
              const int* __restrict__ head, const int* __restrict__ next,
              float* __restrict__ out, int numOut) {
    int gid = blockIdx.x * blockDim.x + threadIdx.x;
    int wave = gid >> 6;
    int lane = threadIdx.x & 63;
    if (wave >= numOut) return;

    int ox = wave & (OD2 - 1);
    int t = wave >> 3;           // OD2 == 8
    int oy = t % OD1;
    t /= OD1;
    int oz = t % OD0;
    int bb = t / OD0;

    unsigned thrBits = ((unsigned)sel[0] << 16) | (unsigned)sel[2];
    float thr = __uint_as_float(thrBits);

    float acc = 0.f;
    int keep = 0;
    int pz0 = 2 * oz - 1, py0 = 2 * oy - 1, px0 = 2 * ox - 1;

    for (int o0 = 0; o0 < 3; o0++) {
        int pz = pz0 + o0;
        if ((unsigned)pz >= (unsigned)IZ) continue;
        for (int o1 = 0; o1 < 3; o1++) {
            int py = py0 + o1;
            if ((unsigned)py >= (unsigned)IY) continue;
            for (int o2 = 0; o2 < 3; o2++) {
                int px = px0 + o2;
                if ((unsigned)px >= (unsigned)IX) continue;
                int cell = ((bb * IZ + pz) * IY + py) * IX + px;
                int p = head[cell];                 // wave-uniform broadcast load
                if (p < 0) continue;
                int tap = (o0 * 3 + o1) * 3 + o2;
                const float4* wp = (const float4*)(Wt + ((size_t)tap * COUT + lane) * CIN);
                float4 w0 = wp[0], w1 = wp[1], w2 = wp[2], w3 = wp[3];
                float4 w4 = wp[4], w5 = wp[5], w6 = wp[6], w7 = wp[7];
                do {
                    int sp = __builtin_amdgcn_readfirstlane(p);   // keep chain walk scalar
                    const float4* fp = (const float4*)(feat + (size_t)sp * CIN);
                    float4 f0 = fp[0], f1 = fp[1], f2 = fp[2], f3 = fp[3];
                    float4 f4 = fp[4], f5 = fp[5], f6 = fp[6], f7 = fp[7];
                    acc = fmaf(f0.x, w0.x, acc); acc = fmaf(f0.y, w0.y, acc);
                    acc = fmaf(f0.z, w0.z, acc); acc = fmaf(f0.w, w0.w, acc);
                    acc = fmaf(f1.x, w1.x, acc); acc = fmaf(f1.y, w1.y, acc);
                    acc = fmaf(f1.z, w1.z, acc); acc = fmaf(f1.w, w1.w, acc);
                    acc = fmaf(f2.x, w2.x, acc); acc = fmaf(f2.y, w2.y, acc);
                    acc = fmaf(f2.z, w2.z, acc); acc = fmaf(f2.w, w2.w, acc);
                    acc = fmaf(f3.x, w3.x, acc); acc = fmaf(f3.y, w3.y, acc);
                    acc = fmaf(f3.z, w3.z, acc); acc = fmaf(f3.w, w3.w, acc);
                    acc = fmaf(f4.x, w4.x, acc); acc = fmaf(f4.y, w4.y, acc);
                    acc = fmaf(f4.z, w4.z, acc); acc = fmaf(f4.w, w4.w, acc);
                    acc = fmaf(f5.x, w5.x, acc); acc = fmaf(f5.y, w5.y, acc);
                    acc = fmaf(f5.z, w5.z, acc); acc = fmaf(f5.w, w5.w, acc);
                    acc = fmaf(f6.x, w6.x, acc); acc = fmaf(f6.y, w6.y, acc);
                    acc = fmaf(f6.z, w6.z, acc); acc = fmaf(f6.w, w6.w, acc);
                    acc = fmaf(f7.x, w7.x, acc); acc = fmaf(f7.y, w7.y, acc);
                    acc = fmaf(f7.z, w7.z, acc); acc = fmaf(f7.w, w7.w, acc);
                    keep |= (mask[sp] >= thr) ? 1 : 0;
                    p = next[sp];
                } while (p >= 0);
            }
        }
    }
    out[(size_t)wave * COUT + lane] = keep ? acc : 0.f;
}

// ---------- legacy scatter path (fallback if workspace too small) ----------

__global__ void __launch_bounds__(256)
scatter_kernel(const float* __restrict__ feat, const int* __restrict__ coors,
               const float* __restrict__ mask, const float* __restrict__ W,
               const int* __restrict__ sel, float* __restrict__ out,
               int* __restrict__ keep, int n) {
    int gid = blockIdx.x * blockDim.x + threadIdx.x;
    int wave = gid >> 6;
    int lane = threadIdx.x & 63;
    if (wave >= n) return;

    const int4 c4 = ((const int4*)coors)[wave];
    int bb = c4.x, pz = c4.y, py = c4.z, px = c4.w;

    unsigned thrBits = ((unsigned)sel[0] << 16) | (unsigned)sel[2];
    float thr = __uint_as_float(thrBits);
    bool imp = mask[wave] >= thr;

    int oz[2], ozo[2], nz = 0;
    int oy[2], oyo[2], ny = 0;
    int ox[2], oxo[2], nx = 0;
#pragma unroll
    for (int o = 0; o < 3; o++) {
        int num = pz + 1 - o;
        if (num >= 0 && !(num & 1) && (num >> 1) < OD0) { oz[nz] = num >> 1; ozo[nz] = o; nz++; }
        num = py + 1 - o;
        if (num >= 0 && !(num & 1) && (num >> 1) < OD1) { oy[ny] = num >> 1; oyo[ny] = o; ny++; }
        num = px + 1 - o;
        if (num >= 0 && !(num & 1) && (num >> 1) < OD2) { ox[nx] = num >> 1; oxo[nx] = o; nx++; }
    }

    float f[CIN];
    const float4* fp = (const float4*)(feat + (size_t)wave * CIN);
#pragma unroll
    for (int j = 0; j < CIN / 4; j++) {
        float4 v = fp[j];
        f[4 * j + 0] = v.x; f[4 * j + 1] = v.y; f[4 * j + 2] = v.z; f[4 * j + 3] = v.w;
    }

    for (int a = 0; a < nz; a++)
        for (int b = 0; b < ny; b++)
            for (int c = 0; c < nx; c++) {
                int woff = ((ozo[a] * 3 + oyo[b]) * 3 + oxo[c]) * (CIN * COUT);
                const float* w = W + woff + lane;
                float acc = 0.f;
#pragma unroll
                for (int k = 0; k < CIN; k++) acc = fmaf(f[k], w[k * COUT], acc);
                int lin = ((bb * OD0 + oz[a]) * OD1 + oy[b]) * OD2 + ox[c];
                atomicAdd(out + (size_t)lin * COUT + lane, acc);
                if (imp && lane == 0) keep[lin] = 1;
            }
}

__global__ void finalize_kernel(float* __restrict__ out, const int* __restrict__ keep, int numOut) {
    int t = blockIdx.x * blockDim.x + threadIdx.x;
    if (t >= numOut * (COUT / 4)) return;
    int o = t >> 4;
    if (!keep[o]) ((float4*)out)[t] = make_float4(0.f, 0.f, 0.f, 0.f);
}

extern "C" void kernel_launch(void* const* d_in, const int* in_sizes, int n_in,
                              void* d_out, int out_size, void* d_ws, size_t ws_size,
                              hipStream_t stream) {
    const float* feat  = (const float*)d_in[0];   // (N, 32) f32
    const int*   coors = (const int*)d_in[1];     // (N, 4)  i32
    const float* mask  = (const float*)d_in[2];   // (N,)    f32
    const float* W     = (const float*)d_in[3];   // (3,3,3,32,64) f32

    int n = in_sizes[2];                 // N (mask element count)
    int numOut = out_size / COUT;        // 160000
    int rank = (int)(n * 0.5);           // int(N * PRUNING_RATIO)

    const int blk = 256;
    int gN = (n + blk - 1) / blk;

    char* ws = (char*)d_ws;

    // workspace layout (gather path)
    size_t offHistHi = 0;                                 // 65536 ints
    size_t offHistLo = 65536 * 4;                         // 65536 ints
    size_t offSel    = 2 * 65536 * 4;                     // 64 B
    size_t offWt     = offSel + 64;                       // 27*32*64 floats = 221184 B
    size_t offHead   = offWt + (size_t)NTAP * CIN * COUT * 4;   // 2*200*200*16 ints
    size_t offNext   = offHead + (size_t)2 * IZ * IY * IX * 4;  // n ints
    size_t need      = offNext + (size_t)n * 4;

    int* histHi = (int*)(ws + offHistHi);
    int* histLo = (int*)(ws + offHistLo);
    int* sel    = (int*)(ws + offSel);

    if (ws_size >= need) {
        float* Wt  = (float*)(ws + offWt);
        int* head  = (int*)(ws + offHead);
        int* next  = (int*)(ws + offNext);

        hipMemsetAsync(ws, 0, offWt, stream);                         // hists + sel
        hipMemsetAsync(head, 0xFF, (size_t)2 * IZ * IY * IX * 4, stream);  // head = -1

        hist_hi_kernel<<<gN, blk, 0, stream>>>(mask, n, histHi);
        select_kernel<<<1, 256, 0, stream>>>(histHi, nullptr, rank, sel);
        hist_lo_kernel<<<gN, blk, 0, stream>>>(mask, n, sel, histLo);
        select_kernel<<<1, 256, 0, stream>>>(histLo, sel + 1, 0, sel + 2);

        int wElems = NTAP * CIN * COUT;
        transpose_w_kernel<<<(wElems + blk - 1) / blk, blk, 0, stream>>>(W, Wt);
        build_grid_kernel<<<gN, blk, 0, stream>>>(coors, n, head, next);

        long long threads = (long long)numOut * 64;
        int gGather = (int)((threads + blk - 1) / blk);
        gather_kernel<<<gGather, blk, 0, stream>>>(feat, mask, Wt, sel,
                                                   head, next, (float*)d_out, numOut);
    } else {
        // legacy scatter path
        int* keep = (int*)(ws + offSel + 64);
        size_t zeroBytes = offSel + 64 + (size_t)numOut * 4;

        hipMemsetAsync(d_out, 0, (size_t)out_size * sizeof(float), stream);
        hipMemsetAsync(d_ws, 0, zeroBytes, stream);

        hist_hi_kernel<<<gN, blk, 0, stream>>>(mask, n, histHi);
        select_kernel<<<1, 256, 0, stream>>>(histHi, nullptr, rank, sel);
        hist_lo_kernel<<<gN, blk, 0, stream>>>(mask, n, sel, histLo);
        select_kernel<<<1, 256, 0, stream>>>(histLo, sel + 1, 0, sel + 2);

        long long threads = (long long)n * 64;
        int gScatter = (int)((threads + blk - 1) / blk);
        scatter_kernel<<<gScatter, blk, 0, stream>>>(feat, coors, mask, W, sel,
                                                     (float*)d_out, keep, n);

        int fin = numOut * (COUT / 4);
        finalize_kernel<<<(fin + blk - 1) / blk, blk, 0, stream>>>((float*)d_out, keep, numOut);
    }
}